// Round 10
// baseline (4232.295 us; speedup 1.0000x reference)
//
#include <hip/hip_runtime.h>
#include <hip/hip_bf16.h>

#define T_DIM 256
#define B_DIM 128
#define C_DIM 1024
#define H_DIM 1024
#define L_DIM 6
#define NC_DIM 1000
#define M_DIM (T_DIM * B_DIM)    // 32768
#define BH_DIM (B_DIM * H_DIM)   // 131072

typedef __attribute__((ext_vector_type(8))) short bf16x8;
typedef __attribute__((ext_vector_type(4))) float f32x4;

__device__ __forceinline__ float bf2f(unsigned short u) {
  union { unsigned int i; float f; } v; v.i = ((unsigned int)u) << 16; return v.f;
}
__device__ __forceinline__ unsigned short f2bf(float f) {
  union { float f; unsigned int i; } v; v.f = f;
  unsigned int r = v.i + 0x7fffu + ((v.i >> 16) & 1u);  // RNE
  return (unsigned short)(r >> 16);
}

__device__ __forceinline__ void gload_lds16(const void* g, void* l) {
  __builtin_amdgcn_global_load_lds(
      (const __attribute__((address_space(1))) unsigned int*)g,
      (__attribute__((address_space(3))) unsigned int*)l, 16, 0, 0);
}

// ---------------- x f32 -> bf16 convert ----------------
__global__ __launch_bounds__(256) void f32_to_bf16_kernel(
    const float* __restrict__ in, unsigned short* __restrict__ out, int n4) {
  int stride = gridDim.x * blockDim.x;
  for (int i = blockIdx.x * blockDim.x + threadIdx.x; i < n4; i += stride) {
    float4 v = ((const float4*)in)[i];
    ushort4 o;
    o.x = f2bf(v.x); o.y = f2bf(v.y); o.z = f2bf(v.z); o.w = f2bf(v.w);
    ((ushort4*)out)[i] = o;
  }
}

// ---------------- W (L,C,H) f32 -> Wt (L,H,C) bf16 ----------------
__global__ __launch_bounds__(256) void wtrans_kernel(
    const float* __restrict__ W, unsigned short* __restrict__ Wt) {
  __shared__ float tile[32][33];
  int l = blockIdx.z;
  const float* Wl = W + (size_t)l * C_DIM * H_DIM;
  unsigned short* Wtl = Wt + (size_t)l * C_DIM * H_DIM;
  int h0 = blockIdx.x * 32, c0 = blockIdx.y * 32;
  int tx = threadIdx.x, ty = threadIdx.y;  // 32 x 8
#pragma unroll
  for (int i = 0; i < 32; i += 8)
    tile[ty + i][tx] = Wl[(size_t)(c0 + ty + i) * H_DIM + h0 + tx];
  __syncthreads();
#pragma unroll
  for (int i = 0; i < 32; i += 8)
    Wtl[(size_t)(h0 + ty + i) * C_DIM + c0 + tx] = f2bf(tile[tx][ty + i]);
}

// ---------------- GEMM 256x512 tile, 16 waves, BK=32, 3-buffer, 1/CU ----------------
// Z(bf16) = A(bf16, MxK) * Wt(bf16, NxK)^T, fused BN partial stats (f32-exact).
// KEY CHANGE vs rounds 2-9: 1024-thread blocks -> 4 waves/SIMD inside ONE barrier
// group (was 2). While one wave sits in its ds_read/lgkm phase, three others feed
// the MFMA pipe (m114 overlap mechanism). Grid = 256 = exactly 1 block/CU ->
// single round, no inter-round tail.
// 16 waves (2M x 8N); per-wave 128x64 out = 8x4 16x16 frags; MFMA 16x16x32.
// LDS 144 KiB = 3 buffers x 48KB {A 16KB (256 rows), B 32KB (512 rows)}.
// Schedule per K-tile: reads + stage(t+2) -> MFMA clusters (compiler interleaves
// via counted lgkmcnt) -> vmcnt(3) [retires stage(t+1)] -> barrier.
// Swizzle: 16B chunk ^= (row>>1)&3 both sides (round-3 verified: 0 conflicts).
#define NT 32  // K / 32

__global__ __launch_bounds__(1024, 4) void gemm_kernel(
    const unsigned short* __restrict__ A, const unsigned short* __restrict__ Bt,
    unsigned short* __restrict__ Z, float* __restrict__ psum, float* __restrict__ psqs) {
  extern __shared__ char lds[];
  int bid = blockIdx.x;              // 256 blocks, %8==0 -> bijective XCD swizzle
  int swz = (bid & 7) * 32 + (bid >> 3);
  int tm = swz >> 1, tn = swz & 1;   // 128 x 2 tiles
  int tid = threadIdx.x;
  int wv = tid >> 6, ln = tid & 63;  // 16 waves
  int wm = wv >> 3, wn = wv & 7;     // 2 x 8 wave grid

  const char* Apanel = (const char*)A + (size_t)tm * 256 * 2048;   // 2048B = K row
  const char* Bpanel = (const char*)Bt + (size_t)tn * 512 * 2048;

  // ---- staging addresses (pre-swizzled global source, linear LDS dest) ----
  // A region 16KB: inst wv covers rows wv*16..wv*16+15
  int pA = wv * 1024 + ln * 16;
  int lA = pA ^ (((pA >> 7) & 3) << 4);            // chunk ^= (row>>1)&3
  size_t goA = (size_t)(pA >> 6) * 2048 + (lA & 63);
  // B region 32KB: insts 2*wv, 2*wv+1
  int pB0 = wv * 2048 + ln * 16;
  int pB1 = pB0 + 1024;
  int lB0 = pB0 ^ (((pB0 >> 7) & 3) << 4);
  int lB1 = pB1 ^ (((pB1 >> 7) & 3) << 4);
  size_t goB0 = (size_t)(pB0 >> 6) * 2048 + (lB0 & 63);
  size_t goB1 = (size_t)(pB1 >> 6) * 2048 + (lB1 & 63);
  int dA = wv * 1024;                               // wave-uniform LDS bases
  int dB0 = 16384 + wv * 2048;
  int dB1 = dB0 + 1024;

  auto stage = [&](int t) {                         // 48KB K-tile, 3 insts/wave
    char* base = lds + (t % 3) * 49152;
    int kb = t * 64;                                // 32 k-elems = 64 bytes
    gload_lds16(Apanel + goA + kb, base + dA);
    gload_lds16(Bpanel + goB0 + kb, base + dB0);
    gload_lds16(Bpanel + goB1 + kb, base + dB1);
  };

  // ---- fragment read offsets (proven 0-conflict pattern) ----
  int frow = ln & 15;
  int fchunk = ((ln >> 4) ^ (frow >> 1)) & 3;
  int floff = frow * 64 + (fchunk << 4);

  f32x4 acc[8][4];
  f32x4 zero = {0.f, 0.f, 0.f, 0.f};
#pragma unroll
  for (int m = 0; m < 8; ++m)
#pragma unroll
    for (int n = 0; n < 4; ++n) acc[m][n] = zero;

  bf16x8 bX[4], aP[4], aQ[4];
  auto readB_to = [&](int t, bf16x8* d) {
    const char* Bb = lds + (t % 3) * 49152 + 16384 + wn * 4096;
#pragma unroll
    for (int n = 0; n < 4; ++n) d[n] = *(const bf16x8*)(Bb + n * 1024 + floff);
  };
  auto readA_to = [&](int t, int mq, bf16x8* d) {
    const char* Ab = lds + (t % 3) * 49152 + wm * 8192 + mq * 4096;
#pragma unroll
    for (int i = 0; i < 4; ++i) d[i] = *(const bf16x8*)(Ab + i * 1024 + floff);
  };

  // prologue: stage tiles 0,1; retire tile 0 (vmcnt 3 = tile 1 in flight)
  stage(0); stage(1);
  asm volatile("s_waitcnt vmcnt(3)" ::: "memory");
  __builtin_amdgcn_s_barrier();

  for (int t = 0; t < NT; ++t) {
    readB_to(t, bX); readA_to(t, 0, aP);
    if (t + 2 < NT) stage(t + 2);
    readA_to(t, 1, aQ);                   // issued before cluster0 consumes aP
    __builtin_amdgcn_s_setprio(1);
#pragma unroll
    for (int i = 0; i < 4; ++i)
#pragma unroll
      for (int n = 0; n < 4; ++n)
        acc[i][n] = __builtin_amdgcn_mfma_f32_16x16x32_bf16(aP[i], bX[n], acc[i][n], 0, 0, 0);
    __builtin_amdgcn_s_setprio(0);
    __builtin_amdgcn_s_setprio(1);
#pragma unroll
    for (int i = 0; i < 4; ++i)
#pragma unroll
      for (int n = 0; n < 4; ++n)
        acc[4 + i][n] = __builtin_amdgcn_mfma_f32_16x16x32_bf16(aQ[i], bX[n], acc[4 + i][n], 0, 0, 0);
    __builtin_amdgcn_s_setprio(0);
    if (t < NT - 1) {
      if (t + 2 < NT) { asm volatile("s_waitcnt vmcnt(3)" ::: "memory"); }  // retire t+1
      else            { asm volatile("s_waitcnt vmcnt(0)" ::: "memory"); }
      __builtin_amdgcn_s_barrier();
    }
  }

  // ---- epilogue: fused BN partial stats (exact f32) + bf16 Z write ----
  // C/D layout: col = ln&15, row = (ln>>4)*4 + reg
  float s[4], q[4];
#pragma unroll
  for (int n = 0; n < 4; ++n) {
    float sv = 0.f, qv = 0.f;
#pragma unroll
    for (int m = 0; m < 8; ++m)
#pragma unroll
      for (int r = 0; r < 4; ++r) {
        float v = acc[m][n][r];
        sv += v; qv += v * v;
      }
    s[n] = sv; q[n] = qv;
  }
#pragma unroll
  for (int n = 0; n < 4; ++n) {
    s[n] += __shfl_xor(s[n], 16); s[n] += __shfl_xor(s[n], 32);
    q[n] += __shfl_xor(q[n], 16); q[n] += __shfl_xor(q[n], 32);
  }
  float* red = (float*)lds;  // buffer-0 region (dead: last used tile 30, pre-barrier)
  __syncthreads();
  if (ln < 16) {
#pragma unroll
    for (int n = 0; n < 4; ++n) {
      red[wm * 512 + wn * 64 + n * 16 + ln] = s[n];
      red[1024 + wm * 512 + wn * 64 + n * 16 + ln] = q[n];
    }
  }
  __syncthreads();
  if (tid < 512) {
    psum[(size_t)tm * H_DIM + tn * 512 + tid] = red[tid] + red[512 + tid];
  } else {
    int c = tid - 512;
    psqs[(size_t)tm * H_DIM + tn * 512 + c] = red[1024 + c] + red[1536 + c];
  }
  // bf16 Z stores
  int r0 = tm * 256 + wm * 128 + ((ln >> 4) << 2);
  int c0 = tn * 512 + wn * 64 + (ln & 15);
#pragma unroll
  for (int m = 0; m < 8; ++m)
#pragma unroll
    for (int n = 0; n < 4; ++n) {
      unsigned short* zp = Z + (size_t)(r0 + m * 16) * H_DIM + c0 + n * 16;
#pragma unroll
      for (int r = 0; r < 4; ++r) zp[(size_t)r * H_DIM] = f2bf(acc[m][n][r]);
    }
}

// ---------------- BN finalize: sum 128 partials per channel ----------------
__global__ __launch_bounds__(256) void bn_finalize_kernel(
    const float* __restrict__ psum, const float* __restrict__ psqs,
    const float* __restrict__ gamma, const float* __restrict__ beta,
    float* __restrict__ ss) {
  int c = blockIdx.x * blockDim.x + threadIdx.x;
  float s = 0.f, q = 0.f;
  for (int i = 0; i < 128; ++i) {
    s += psum[(size_t)i * H_DIM + c];
    q += psqs[(size_t)i * H_DIM + c];
  }
  const float invN = 1.0f / (float)M_DIM;
  float mean = s * invN;
  float var = q * invN - mean * mean;
  float sc = gamma[c] * rsqrtf(var + 1e-5f);
  ss[c] = sc;
  ss[H_DIM + c] = beta[c] - mean * sc;
}

// ---------------- fused BN-apply + IndRNN recurrence (1 ch/thread, bf16 Z) ----------------
// 512 blocks (8 waves/CU); 32-deep static double-buffered prefetch (rule #20).
__global__ __launch_bounds__(256) void bn_recur_kernel(
    const unsigned short* __restrict__ Z, const float* __restrict__ ss,
    const float* __restrict__ u, unsigned short* __restrict__ Hout) {
  int i = blockIdx.x * 256 + threadIdx.x;   // 0..BH-1
  int h = i & (H_DIM - 1);
  float sc = ss[h], sh = ss[H_DIM + h], uu = u[h];
  float hv = 0.f;
  const unsigned short* Zt = Z + i;
  unsigned short* Ht = Hout + i;

  unsigned short za[32], zb[32];
#pragma unroll
  for (int j = 0; j < 32; ++j) za[j] = Zt[(size_t)j * BH_DIM];

#pragma unroll
  for (int blk = 0; blk < 4; ++blk) {
    int tA = blk * 64;
#pragma unroll
    for (int j = 0; j < 32; ++j) zb[j] = Zt[(size_t)(tA + 32 + j) * BH_DIM];
#pragma unroll
    for (int j = 0; j < 32; ++j) {
      float z = fmaf(bf2f(za[j]), sc, sh);
      hv = fmaxf(fmaf(uu, hv, z), 0.f);
      Ht[(size_t)(tA + j) * BH_DIM] = f2bf(hv);
    }
    if (blk < 3) {
#pragma unroll
      for (int j = 0; j < 32; ++j) za[j] = Zt[(size_t)(tA + 64 + j) * BH_DIM];
    }
#pragma unroll
    for (int j = 0; j < 32; ++j) {
      float z = fmaf(bf2f(zb[j]), sc, sh);
      hv = fmaxf(fmaf(uu, hv, z), 0.f);
      Ht[(size_t)(tA + 32 + j) * BH_DIM] = f2bf(hv);
    }
  }
}

// ---------------- classifier ----------------
__global__ __launch_bounds__(256) void classifier_kernel(
    const unsigned short* __restrict__ hlast, const float* __restrict__ Wc,
    const float* __restrict__ bc, float* __restrict__ out) {
  __shared__ float hs[H_DIM];
  int b = blockIdx.y;
  int n = blockIdx.x * 256 + threadIdx.x;
  for (int k = threadIdx.x; k < H_DIM; k += 256)
    hs[k] = bf2f(hlast[(size_t)b * H_DIM + k]);
  __syncthreads();
  if (n < NC_DIM) {
    float acc = bc[n];
#pragma unroll 8
    for (int k = 0; k < H_DIM; ++k)
      acc = fmaf(hs[k], Wc[(size_t)k * NC_DIM + n], acc);
    out[(size_t)b * NC_DIM + n] = acc;
  }
}

extern "C" void kernel_launch(void* const* d_in, const int* in_sizes, int n_in,
                              void* d_out, int out_size, void* d_ws, size_t ws_size,
                              hipStream_t stream) {
  const float* x     = (const float*)d_in[0];
  const float* W     = (const float*)d_in[1];
  // d_in[2] = b: cancels under BatchNorm (shift-invariant)
  const float* gamma = (const float*)d_in[3];
  const float* beta  = (const float*)d_in[4];
  const float* u     = (const float*)d_in[5];
  const float* Wc    = (const float*)d_in[6];
  const float* bc    = (const float*)d_in[7];
  float* out = (float*)d_out;

  const size_t CH = (size_t)C_DIM * H_DIM;
  const size_t MH = (size_t)M_DIM * H_DIM;
  char* p = (char*)d_ws;
  unsigned short* Wt = (unsigned short*)p; p += L_DIM * CH * sizeof(unsigned short);
  unsigned short* Ha = (unsigned short*)p; p += MH * sizeof(unsigned short);
  unsigned short* Hb = (unsigned short*)p; p += MH * sizeof(unsigned short);
  unsigned short* Z  = (unsigned short*)p; p += MH * sizeof(unsigned short);
  float* psum = (float*)p; p += 128 * H_DIM * sizeof(float);
  float* psqs = (float*)p; p += 128 * H_DIM * sizeof(float);
  float* ss   = (float*)p; p += 2 * H_DIM * sizeof(float);

  f32_to_bf16_kernel<<<2048, 256, 0, stream>>>(x, Ha, (int)(MH / 4));
  wtrans_kernel<<<dim3(H_DIM / 32, C_DIM / 32, L_DIM), dim3(32, 8), 0, stream>>>(W, Wt);

  unsigned short* cur = Ha;
  unsigned short* nxt = Hb;
  for (int l = 0; l < L_DIM; ++l) {
    gemm_kernel<<<(M_DIM / 256) * (H_DIM / 512), 1024, 147456, stream>>>(
        cur, Wt + (size_t)l * CH, Z, psum, psqs);
    bn_finalize_kernel<<<4, 256, 0, stream>>>(psum, psqs, gamma + (size_t)l * H_DIM,
                                              beta + (size_t)l * H_DIM, ss);
    bn_recur_kernel<<<BH_DIM / 256, 256, 0, stream>>>(Z, ss, u + (size_t)l * H_DIM, nxt);
    unsigned short* tmp = cur; cur = nxt; nxt = tmp;
  }
  classifier_kernel<<<dim3(4, B_DIM), 256, 0, stream>>>(
      cur + (size_t)(T_DIM - 1) * BH_DIM, Wc, bc, out);
}

// Round 11
// 754.181 us; speedup vs baseline: 5.6118x; 5.6118x over previous
//
#include <hip/hip_runtime.h>
#include <hip/hip_bf16.h>

#define T_DIM 256
#define B_DIM 128
#define C_DIM 1024
#define H_DIM 1024
#define L_DIM 6
#define NC_DIM 1000
#define M_DIM (T_DIM * B_DIM)    // 32768
#define BH_DIM (B_DIM * H_DIM)   // 131072

typedef __attribute__((ext_vector_type(8))) short bf16x8;
typedef __attribute__((ext_vector_type(4))) float f32x4;

__device__ __forceinline__ float bf2f(unsigned short u) {
  union { unsigned int i; float f; } v; v.i = ((unsigned int)u) << 16; return v.f;
}
__device__ __forceinline__ unsigned short f2bf(float f) {
  union { float f; unsigned int i; } v; v.f = f;
  unsigned int r = v.i + 0x7fffu + ((v.i >> 16) & 1u);  // RNE
  return (unsigned short)(r >> 16);
}

__device__ __forceinline__ void gload_lds16(const void* g, void* l) {
  __builtin_amdgcn_global_load_lds(
      (const __attribute__((address_space(1))) unsigned int*)g,
      (__attribute__((address_space(3))) unsigned int*)l, 16, 0, 0);
}

// ---------------- x f32 -> bf16 convert ----------------
__global__ __launch_bounds__(256) void f32_to_bf16_kernel(
    const float* __restrict__ in, unsigned short* __restrict__ out, int n4) {
  int stride = gridDim.x * blockDim.x;
  for (int i = blockIdx.x * blockDim.x + threadIdx.x; i < n4; i += stride) {
    float4 v = ((const float4*)in)[i];
    ushort4 o;
    o.x = f2bf(v.x); o.y = f2bf(v.y); o.z = f2bf(v.z); o.w = f2bf(v.w);
    ((ushort4*)out)[i] = o;
  }
}

// ---------------- W (L,C,H) f32 -> Wt (L,H,C) bf16 ----------------
__global__ __launch_bounds__(256) void wtrans_kernel(
    const float* __restrict__ W, unsigned short* __restrict__ Wt) {
  __shared__ float tile[32][33];
  int l = blockIdx.z;
  const float* Wl = W + (size_t)l * C_DIM * H_DIM;
  unsigned short* Wtl = Wt + (size_t)l * C_DIM * H_DIM;
  int h0 = blockIdx.x * 32, c0 = blockIdx.y * 32;
  int tx = threadIdx.x, ty = threadIdx.y;  // 32 x 8
#pragma unroll
  for (int i = 0; i < 32; i += 8)
    tile[ty + i][tx] = Wl[(size_t)(c0 + ty + i) * H_DIM + h0 + tx];
  __syncthreads();
#pragma unroll
  for (int i = 0; i < 32; i += 8)
    Wtl[(size_t)(h0 + ty + i) * C_DIM + c0 + tx] = f2bf(tile[tx][ty + i]);
}

// ---------------- GEMM 256x256, BK=32, 4-buffer pipeline, 2 tiles/block ----------------
// Z(bf16) = A(bf16, MxK) * Wt(bf16, NxK)^T, fused BN partial stats (f32-exact).
// Round-9 schedule (best measured: ~890 TF): 8 waves (2M x 4N), per-wave 128x64
// out = 8x4 16x16 frags; ds_reads one batch ahead in named regs; ONE barrier +
// counted vmcnt(4) per K-tile; 0-conflict swizzle (chunk ^= (row>>1)&3).
// NEW: grid 256 = 1 block/CU, each block does 2 M-adjacent tiles with the SAME
// tn (B-panel stays L2-hot). Tile-2's 3-tile staging prologue is issued BEFORE
// tile-1's epilogue so HBM latency hides under stats+Z-stores; red lives in the
// buffer-3 region (not touched by stage(0..2)); barriers fence red vs re-staging.
#define NT 32  // K / 32

__global__ __launch_bounds__(512, 2) void gemm_kernel(
    const unsigned short* __restrict__ A, const unsigned short* __restrict__ Bt,
    unsigned short* __restrict__ Z, float* __restrict__ psum, float* __restrict__ psqs) {
  extern __shared__ char lds[];
  int bid = blockIdx.x;              // 256 blocks, %8==0 -> bijective XCD swizzle
  int swz = (bid & 7) * 32 + (bid >> 3);
  int tm0 = (swz >> 2) * 2;          // tiles (tm0, tn) and (tm0+1, tn)
  int tn = swz & 3;
  int tid = threadIdx.x;
  int wv = tid >> 6, ln = tid & 63;
  int wm = wv >> 2, wn = wv & 3;     // 2 x 4 wave grid

  const char* Ap0 = (const char*)A + (size_t)tm0 * 256 * 2048;        // 2048B = K row
  const char* Ap1 = Ap0 + (size_t)256 * 2048;
  const char* Bpanel = (const char*)Bt + (size_t)tn * 256 * 2048;

  // ---- staging addresses (pre-swizzled global source, linear LDS dest) ----
  int p0 = wv * 1024 + ln * 16;           // byte within an 8KB (128-row) half
  int l0 = p0 ^ (((p0 >> 7) & 3) << 4);   // involution: chunk ^= (row>>1)&3
  size_t ro0 = (size_t)(p0 >> 6) * 2048 + (l0 & 63);          // rows 0..127
  size_t ro1 = (size_t)(128 + (p0 >> 6)) * 2048 + (l0 & 63);  // rows 128..255
  int sdst = wv * 1024;                   // wave-uniform (+ lane*16 by HW)

  auto stage = [&](const char* Ap, int t) {  // one 32KB K-tile: A 16KB + B 16KB
    char* base = lds + ((t & 3) * 32768);
    int kb = t * 64;                      // 32 k-elems = 64 bytes
    gload_lds16(Ap + ro0 + kb, base + sdst);
    gload_lds16(Ap + ro1 + kb, base + 8192 + sdst);
    gload_lds16(Bpanel + ro0 + kb, base + 16384 + sdst);
    gload_lds16(Bpanel + ro1 + kb, base + 16384 + 8192 + sdst);
  };

  // ---- fragment read offsets (proven 0-conflict pattern) ----
  int frow = ln & 15;
  int fchunk = ((ln >> 4) ^ (frow >> 1)) & 3;
  int floff = frow * 64 + (fchunk << 4);

  f32x4 acc[8][4];

  bf16x8 bX[4], aP[4], aQ[4];
  auto readB_to = [&](int t, bf16x8* d) {
    const char* Bb = lds + ((t & 3) * 32768) + 16384 + wn * 4096;
#pragma unroll
    for (int n = 0; n < 4; ++n) d[n] = *(const bf16x8*)(Bb + n * 1024 + floff);
  };
  auto readA_to = [&](int t, int mq, bf16x8* d) {
    const char* Ab = lds + ((t & 3) * 32768) + wm * 8192 + mq * 4096;
#pragma unroll
    for (int i = 0; i < 4; ++i) d[i] = *(const bf16x8*)(Ab + i * 1024 + floff);
  };

  auto kloop = [&](const char* Ap) {
    f32x4 zero = {0.f, 0.f, 0.f, 0.f};
#pragma unroll
    for (int m = 0; m < 8; ++m)
#pragma unroll
      for (int n = 0; n < 4; ++n) acc[m][n] = zero;
    readB_to(0, bX); readA_to(0, 0, aP);
    for (int t = 0; t < NT; ++t) {
      readA_to(t, 1, aQ);                  // batch1: overlaps cluster0 below
      if (t <= NT - 4) stage(Ap, t + 3);
      __builtin_amdgcn_s_setprio(1);
#pragma unroll
      for (int i = 0; i < 4; ++i)
#pragma unroll
        for (int n = 0; n < 4; ++n)
          acc[i][n] = __builtin_amdgcn_mfma_f32_16x16x32_bf16(aP[i], bX[n], acc[i][n], 0, 0, 0);
      __builtin_amdgcn_s_setprio(0);
      __builtin_amdgcn_s_setprio(1);
#pragma unroll
      for (int i = 0; i < 4; ++i)
#pragma unroll
        for (int n = 0; n < 4; ++n)
          acc[4 + i][n] = __builtin_amdgcn_mfma_f32_16x16x32_bf16(aQ[i], bX[n], acc[4 + i][n], 0, 0, 0);
      __builtin_amdgcn_s_setprio(0);
      if (t < NT - 1) {
        readB_to(t + 1, bX); readA_to(t + 1, 0, aP);   // batch0(t+1)
        if (t <= NT - 4) { asm volatile("s_waitcnt vmcnt(4)" ::: "memory"); }
        else             { asm volatile("s_waitcnt vmcnt(0)" ::: "memory"); }
        __builtin_amdgcn_s_barrier();      // staging(t+2) visible
      }
    }
  };

  // epilogue: fused BN partial stats (exact f32) + bf16 Z write.
  // C/D layout: col = ln&15, row = (ln>>4)*4 + reg
  float* red = (float*)(lds + 3 * 32768);  // buffer-3 region
  auto epilogue = [&](int tm) {
    float s[4], q[4];
#pragma unroll
    for (int n = 0; n < 4; ++n) {
      float sv = 0.f, qv = 0.f;
#pragma unroll
      for (int m = 0; m < 8; ++m)
#pragma unroll
        for (int r = 0; r < 4; ++r) {
          float v = acc[m][n][r];
          sv += v; qv += v * v;
        }
      s[n] = sv; q[n] = qv;
    }
#pragma unroll
    for (int n = 0; n < 4; ++n) {
      s[n] += __shfl_xor(s[n], 16); s[n] += __shfl_xor(s[n], 32);
      q[n] += __shfl_xor(q[n], 16); q[n] += __shfl_xor(q[n], 32);
    }
    if (ln < 16) {
#pragma unroll
      for (int n = 0; n < 4; ++n) {
        red[wm * 256 + wn * 64 + n * 16 + ln] = s[n];
        red[512 + wm * 256 + wn * 64 + n * 16 + ln] = q[n];
      }
    }
    __syncthreads();
    if (tid < 256) {
      psum[(size_t)tm * H_DIM + tn * 256 + tid] = red[tid] + red[256 + tid];
    } else {
      int c = tid - 256;
      psqs[(size_t)tm * H_DIM + tn * 256 + c] = red[512 + c] + red[768 + c];
    }
    __syncthreads();   // red consumed; safe for next tile's reuse
    int r0 = tm * 256 + wm * 128 + ((ln >> 4) << 2);
    int c0 = tn * 256 + wn * 64 + (ln & 15);
#pragma unroll
    for (int m = 0; m < 8; ++m)
#pragma unroll
      for (int n = 0; n < 4; ++n) {
        unsigned short* zp = Z + (size_t)(r0 + m * 16) * H_DIM + c0 + n * 16;
#pragma unroll
        for (int r = 0; r < 4; ++r) zp[(size_t)r * H_DIM] = f2bf(acc[m][n][r]);
      }
  };

  // ---- tile 1 ----
  stage(Ap0, 0); stage(Ap0, 1); stage(Ap0, 2);
  asm volatile("s_waitcnt vmcnt(4)" ::: "memory");
  __builtin_amdgcn_s_barrier();
  kloop(Ap0);
  __builtin_amdgcn_s_barrier();            // all reads of bufs done
  // ---- tile 2 staging overlapped with tile-1 epilogue ----
  stage(Ap1, 0); stage(Ap1, 1); stage(Ap1, 2);
  epilogue(tm0);
  asm volatile("s_waitcnt vmcnt(4)" ::: "memory");  // 12 loads (+most stores) retired
  __builtin_amdgcn_s_barrier();
  kloop(Ap1);
  __builtin_amdgcn_s_barrier();
  epilogue(tm0 + 1);
}

// ---------------- fused BN-finalize + BN-apply + IndRNN recurrence ----------------
// Each thread owns one channel h: reduces its 128 psum/psqs partials itself
// (replaces the separate bn_finalize dispatch), then runs the recurrence.
// 512 blocks (8 waves/CU); 32-deep static double-buffered prefetch (rule #20).
__global__ __launch_bounds__(256) void bn_recur_kernel(
    const unsigned short* __restrict__ Z, const float* __restrict__ psum,
    const float* __restrict__ psqs, const float* __restrict__ gamma,
    const float* __restrict__ beta, const float* __restrict__ u,
    unsigned short* __restrict__ Hout) {
  int i = blockIdx.x * 256 + threadIdx.x;   // 0..BH-1
  int h = i & (H_DIM - 1);
  // finalize BN stats for channel h
  float s = 0.f, q = 0.f;
#pragma unroll 8
  for (int j = 0; j < 128; ++j) {
    s += psum[(size_t)j * H_DIM + h];
    q += psqs[(size_t)j * H_DIM + h];
  }
  const float invN = 1.0f / (float)M_DIM;
  float mean = s * invN;
  float var = q * invN - mean * mean;
  float sc = gamma[h] * rsqrtf(var + 1e-5f);
  float sh = beta[h] - mean * sc;
  float uu = u[h];

  float hv = 0.f;
  const unsigned short* Zt = Z + i;
  unsigned short* Ht = Hout + i;

  unsigned short za[32], zb[32];
#pragma unroll
  for (int j = 0; j < 32; ++j) za[j] = Zt[(size_t)j * BH_DIM];

#pragma unroll
  for (int blk = 0; blk < 4; ++blk) {
    int tA = blk * 64;
#pragma unroll
    for (int j = 0; j < 32; ++j) zb[j] = Zt[(size_t)(tA + 32 + j) * BH_DIM];
#pragma unroll
    for (int j = 0; j < 32; ++j) {
      float z = fmaf(bf2f(za[j]), sc, sh);
      hv = fmaxf(fmaf(uu, hv, z), 0.f);
      Ht[(size_t)(tA + j) * BH_DIM] = f2bf(hv);
    }
    if (blk < 3) {
#pragma unroll
      for (int j = 0; j < 32; ++j) za[j] = Zt[(size_t)(tA + 64 + j) * BH_DIM];
    }
#pragma unroll
    for (int j = 0; j < 32; ++j) {
      float z = fmaf(bf2f(zb[j]), sc, sh);
      hv = fmaxf(fmaf(uu, hv, z), 0.f);
      Ht[(size_t)(tA + 32 + j) * BH_DIM] = f2bf(hv);
    }
  }
}

// ---------------- classifier ----------------
__global__ __launch_bounds__(256) void classifier_kernel(
    const unsigned short* __restrict__ hlast, const float* __restrict__ Wc,
    const float* __restrict__ bc, float* __restrict__ out) {
  __shared__ float hs[H_DIM];
  int b = blockIdx.y;
  int n = blockIdx.x * 256 + threadIdx.x;
  for (int k = threadIdx.x; k < H_DIM; k += 256)
    hs[k] = bf2f(hlast[(size_t)b * H_DIM + k]);
  __syncthreads();
  if (n < NC_DIM) {
    float acc = bc[n];
#pragma unroll 8
    for (int k = 0; k < H_DIM; ++k)
      acc = fmaf(hs[k], Wc[(size_t)k * NC_DIM + n], acc);
    out[(size_t)b * NC_DIM + n] = acc;
  }
}

extern "C" void kernel_launch(void* const* d_in, const int* in_sizes, int n_in,
                              void* d_out, int out_size, void* d_ws, size_t ws_size,
                              hipStream_t stream) {
  const float* x     = (const float*)d_in[0];
  const float* W     = (const float*)d_in[1];
  // d_in[2] = b: cancels under BatchNorm (shift-invariant)
  const float* gamma = (const float*)d_in[3];
  const float* beta  = (const float*)d_in[4];
  const float* u     = (const float*)d_in[5];
  const float* Wc    = (const float*)d_in[6];
  const float* bc    = (const float*)d_in[7];
  float* out = (float*)d_out;

  const size_t CH = (size_t)C_DIM * H_DIM;
  const size_t MH = (size_t)M_DIM * H_DIM;
  char* p = (char*)d_ws;
  unsigned short* Wt = (unsigned short*)p; p += L_DIM * CH * sizeof(unsigned short);
  unsigned short* Ha = (unsigned short*)p; p += MH * sizeof(unsigned short);
  unsigned short* Hb = (unsigned short*)p; p += MH * sizeof(unsigned short);
  unsigned short* Z  = (unsigned short*)p; p += MH * sizeof(unsigned short);
  float* psum = (float*)p; p += 128 * H_DIM * sizeof(float);
  float* psqs = (float*)p; p += 128 * H_DIM * sizeof(float);

  f32_to_bf16_kernel<<<2048, 256, 0, stream>>>(x, Ha, (int)(MH / 4));
  wtrans_kernel<<<dim3(H_DIM / 32, C_DIM / 32, L_DIM), dim3(32, 8), 0, stream>>>(W, Wt);

  unsigned short* cur = Ha;
  unsigned short* nxt = Hb;
  for (int l = 0; l < L_DIM; ++l) {
    gemm_kernel<<<256, 512, 131072, stream>>>(cur, Wt + (size_t)l * CH, Z, psum, psqs);
    bn_recur_kernel<<<BH_DIM / 256, 256, 0, stream>>>(
        Z, psum, psqs, gamma + (size_t)l * H_DIM, beta + (size_t)l * H_DIM,
        u + (size_t)l * H_DIM, nxt);
    unsigned short* tmp = cur; cur = nxt; nxt = tmp;
  }
  classifier_kernel<<<dim3(4, B_DIM), 256, 0, stream>>>(
      cur + (size_t)(T_DIM - 1) * BH_DIM, Wc, bc, out);
}